// Round 10
// baseline (323.687 us; speedup 1.0000x reference)
//
#include <hip/hip_runtime.h>
#include <hip/hip_bf16.h>

#define BATCH   64
#define C_IN    512
#define C_OUT   512
#define SPATIAL 784          // 28*28
#define KSMALL  256          // K = C_OUT * 0.5
#define RATE    0.5f

// ---------------------------------------------------------------------------
// Kernel 1: s[b][c] = mean(|x[b,c,:,:]|).  One pair per wave (exact R4
// config -- best measured, 172.9us total).  Also zeroes the 64 per-row
// completion counters used by kernel 2 (kernel-boundary ordering makes
// them visible -- same guarantee `s` relies on).
// ---------------------------------------------------------------------------
__global__ __launch_bounds__(256) void absmean_kernel(const float* __restrict__ x,
                                                      float* __restrict__ s,
                                                      unsigned int* __restrict__ cnt) {
    if (blockIdx.x == 0 && threadIdx.x < BATCH) cnt[threadIdx.x] = 0;

    const int gwave = (blockIdx.x * blockDim.x + threadIdx.x) >> 6;  // pair id
    const int lane  = threadIdx.x & 63;
    if (gwave >= BATCH * C_IN) return;

    const float4* p = reinterpret_cast<const float4*>(x + (size_t)gwave * SPATIAL);
    float acc = 0.0f;
#pragma unroll
    for (int j = 0; j < 3; ++j) {                 // 192 float4
        float4 v = p[lane + 64 * j];
        acc += fabsf(v.x) + fabsf(v.y) + fabsf(v.z) + fabsf(v.w);
    }
    if (lane < 4) {                               // tail 4 float4
        float4 v = p[192 + lane];
        acc += fabsf(v.x) + fabsf(v.y) + fabsf(v.z) + fabsf(v.w);
    }
#pragma unroll
    for (int off = 32; off; off >>= 1) acc += __shfl_xor(acc, off);
    if (lane == 0) s[gwave] = acc * (1.0f / (float)SPATIAL);
}

// ---------------------------------------------------------------------------
// Kernel 2 (fused, full-width): gate GEMV at the R4-measured structure
// (2048 blocks, 4 outputs/wave) + last-block-per-row topk.  Each row has
// 32 blocks; after a block stores its 16 g values it does
// threadfence -> atomicAdd(row counter); the block seeing old==31 runs the
// topk+renorm for that row (threadfence-reduction pattern: device-scope
// atomic + agent fences give cross-XCD visibility; no dispatch-order
// assumption).  Saves one graph node vs R8 and overlaps topk under gemv.
// ---------------------------------------------------------------------------
__global__ __launch_bounds__(256) void gemv_topk_kernel(const float* __restrict__ s,
                                                        const float* __restrict__ W,
                                                        const float* __restrict__ bias,
                                                        float* __restrict__ g,
                                                        unsigned int* __restrict__ cnt,
                                                        float* __restrict__ out) {
    const int blk  = blockIdx.x;         // 0..2047
    const int t    = threadIdx.x;        // 0..255
    const int lane = t & 63;
    const int wid  = t >> 6;             // 0..3
    const int b    = blk >> 5;           // row: 32 blocks per row
    const int c0   = (blk & 31) * 16 + wid * 4;   // this wave's 4 outputs

    __shared__ float sh_g[C_OUT];
    __shared__ float sh_red[4];
    __shared__ int   sh_last;

    // ---- GEMV: 4 outputs per wave (R4-measured structure, untouched) ----
    const float* sr = s + b * C_IN;
    float s_reg[8];
#pragma unroll
    for (int j = 0; j < 8; ++j) s_reg[j] = sr[lane + 64 * j];

    float acc[4];
#pragma unroll
    for (int o = 0; o < 4; ++o) {
        const float* wr = W + (size_t)(c0 + o) * (C_IN + 1);
        float a = 0.0f;
#pragma unroll
        for (int j = 0; j < 8; ++j) a += wr[lane + 64 * j] * s_reg[j];
        if (lane == 0) a += RATE * wr[C_IN];         // rate column
        acc[o] = a;
    }
#pragma unroll
    for (int off = 32; off; off >>= 1) {
#pragma unroll
        for (int o = 0; o < 4; ++o) acc[o] += __shfl_xor(acc[o], off);
    }
    if (lane == 0) {
        float4 r;
        r.x = fmaxf(acc[0] + bias[c0 + 0], 0.0f);
        r.y = fmaxf(acc[1] + bias[c0 + 1], 0.0f);
        r.z = fmaxf(acc[2] + bias[c0 + 2], 0.0f);
        r.w = fmaxf(acc[3] + bias[c0 + 3], 0.0f);
        *reinterpret_cast<float4*>(g + b * C_OUT + c0) = r;
    }

    // ---- completion signal (threadfence-reduction pattern) ----
    __threadfence();                     // release: g stores visible device-wide
    __syncthreads();
    if (t == 0) {
        unsigned int old = atomicAdd(&cnt[b], 1u);
        sh_last = (old == 31u);
    }
    __syncthreads();
    if (!sh_last) return;
    __threadfence();                     // acquire: see other blocks' g stores

    // ---- topk + renorm for row b (256 threads, 2 channels each) ----
    const float gv0 = g[b * C_OUT + t];
    const float gv1 = g[b * C_OUT + t + 256];
    sh_g[t]       = gv0;
    sh_g[t + 256] = gv1;
    __syncthreads();

    // stable rank: #{g_j < g_t} + #{j<t : g_j == g_t}  (lax.top_k tie-break,
    // absmax 0.0 across R2-R8)
    const float4* shv = reinterpret_cast<const float4*>(sh_g);
    int rank0 = 0, rank1 = 0;
    const int t1 = t + 256;
#pragma unroll 8
    for (int j4 = 0; j4 < C_OUT / 4; ++j4) {
        const float4 v = shv[j4];
        const int j = j4 * 4;
        rank0 += (v.x < gv0) | ((v.x == gv0) & (j + 0 < t));
        rank0 += (v.y < gv0) | ((v.y == gv0) & (j + 1 < t));
        rank0 += (v.z < gv0) | ((v.z == gv0) & (j + 2 < t));
        rank0 += (v.w < gv0) | ((v.w == gv0) & (j + 3 < t));
        rank1 += (v.x < gv1) | ((v.x == gv1) & (j + 0 < t1));
        rank1 += (v.y < gv1) | ((v.y == gv1) & (j + 1 < t1));
        rank1 += (v.z < gv1) | ((v.z == gv1) & (j + 2 < t1));
        rank1 += (v.w < gv1) | ((v.w == gv1) & (j + 3 < t1));
    }
    const float kept0 = (rank0 >= KSMALL) ? gv0 : 0.0f;
    const float kept1 = (rank1 >= KSMALL) ? gv1 : 0.0f;

    float sum = kept0 + kept1;
#pragma unroll
    for (int off = 32; off; off >>= 1) sum += __shfl_xor(sum, off);
    if (lane == 0) sh_red[wid] = sum;
    __syncthreads();
    if (t == 0) sh_red[0] = (sh_red[0] + sh_red[1]) + (sh_red[2] + sh_red[3]);
    __syncthreads();

    const float scale = (float)C_OUT / sh_red[0];
    out[b * C_OUT + t]       = kept0 * scale;
    out[b * C_OUT + t + 256] = kept1 * scale;
}

// ---------------------------------------------------------------------------
extern "C" void kernel_launch(void* const* d_in, const int* in_sizes, int n_in,
                              void* d_out, int out_size, void* d_ws, size_t ws_size,
                              hipStream_t stream) {
    const float* x    = (const float*)d_in[0];   // [64,512,28,28]
    const float* W    = (const float*)d_in[1];   // [512,513]
    const float* bias = (const float*)d_in[2];   // [512]
    float* out        = (float*)d_out;           // [64,512] (x1x1)
    float* s          = (float*)d_ws;                            // [64,512]
    float* g          = (float*)d_ws + BATCH * C_IN;             // [64,512]
    unsigned int* cnt = (unsigned int*)((float*)d_ws + 2 * BATCH * C_IN); // [64]

    // Phase 1: abs-mean (R4 config) + counter zeroing. 8192 blocks.
    absmean_kernel<<<BATCH * C_IN / 4, 256, 0, stream>>>(x, s, cnt);

    // Phase 2+3 fused: GEMV (2048 blocks) + last-block-per-row topk.
    gemv_topk_kernel<<<BATCH * C_OUT / 16, 256, 0, stream>>>(s, W, bias, g, cnt, out);
}